// Round 6
// baseline (427.487 us; speedup 1.0000x reference)
//
#include <hip/hip_runtime.h>

typedef __bf16 bf16x8 __attribute__((ext_vector_type(8)));
typedef float f32x4 __attribute__((ext_vector_type(4)));

// ---------------- sizes ----------------
// B=8, LAT=512, CIN=F=256, Hin=Win=64, H=W=128, K=3
// ws layout (bytes):
//   xu_p NHWC bf16 [8][130][130][256] : off 0          size 69222400
//   y1_p NHWC bf16 [8][130][130][256] : off 69222400   size 69222400
//   wm   bf16 [8][256][9][256]        : off 138444800  size 9437184   (reused)
//   sbuf f32 [2][8][256]              : off 147881984  size 16384

#define GLDS(gsrc, ldst) __builtin_amdgcn_global_load_lds( \
    (const __attribute__((address_space(1))) unsigned int*)(gsrc), \
    (__attribute__((address_space(3))) unsigned int*)(ldst), 16, 0, 0)

#define MFMA(a, b, c) __builtin_amdgcn_mfma_f32_16x16x32_bf16((a), (b), (c), 0, 0, 0)

// ---------------- styles ----------------
__global__ void style_kernel(const float* __restrict__ istyle,
                             const float* __restrict__ ws1, const float* __restrict__ bs1,
                             const float* __restrict__ ws2, const float* __restrict__ bs2,
                             float* __restrict__ sbuf) {
    int b = blockIdx.x;
    int which = blockIdx.y;
    int c = threadIdx.x;
    const float* ws = which ? ws2 : ws1;
    const float* bs = which ? bs2 : bs1;
    __shared__ float st[512];
    for (int i = threadIdx.x; i < 512; i += 256) st[i] = istyle[b * 512 + i];
    __syncthreads();
    float acc = bs[c];
    const float* wr = ws + (size_t)c * 512;
    for (int l = 0; l < 512; ++l) acc += st[l] * wr[l];
    sbuf[((size_t)which * 8 + b) * 256 + c] = acc;
}

// ---------------- modulate + demodulate -> bf16 [b][o][tap][c] ----------------
__global__ void modw_kernel(const float* __restrict__ w, const float* __restrict__ s,
                            __bf16* __restrict__ wm) {
    int wv = threadIdx.x >> 6, lane = threadIdx.x & 63;
    int idx = blockIdx.x * 4 + wv;      // 0..2047
    int b = idx >> 8, o = idx & 255;
    int c0 = lane * 4;
    const float* wr = w + ((size_t)o * 256 + c0) * 9;
    const float* sb = s + (size_t)b * 256 + c0;
    float v[36];
    float ss = 0.f;
#pragma unroll
    for (int cc = 0; cc < 4; ++cc) {
        float sm = sb[cc] + 1.0f;
#pragma unroll
        for (int t = 0; t < 9; ++t) {
            float x = wr[cc * 9 + t] * sm;
            v[cc * 9 + t] = x;
            ss += x * x;
        }
    }
#pragma unroll
    for (int off = 32; off > 0; off >>= 1) ss += __shfl_xor(ss, off);
    float d = rsqrtf(ss + 1e-8f);
    __bf16* wp = wm + ((size_t)(b * 256 + o) * 9) * 256 + c0;
#pragma unroll
    for (int t = 0; t < 9; ++t) {
        union { __bf16 h[4]; uint2 u; } pk;
#pragma unroll
        for (int cc = 0; cc < 4; ++cc) pk.h[cc] = (__bf16)(v[cc * 9 + t] * d);
        *(uint2*)(wp + (size_t)t * 256) = pk.u;
    }
}

// ---------------- zero the 1-pixel border ----------------
__global__ void zeropad_kernel(__bf16* __restrict__ xu, __bf16* __restrict__ y1) {
    int p0 = blockIdx.x * 8;
    int b  = blockIdx.y;
    __bf16* buf = blockIdx.z ? y1 : xu;
    int p = p0 + (threadIdx.x >> 5);
    if (p >= 516) return;
    int chunk = threadIdx.x & 31;
    int y, x;
    if (p < 130)      { y = 0;           x = p; }
    else if (p < 260) { y = 129;         x = p - 130; }
    else if (p < 388) { y = p - 260 + 1; x = 0; }
    else              { y = p - 388 + 1; x = 129; }
    uint4 z = make_uint4(0, 0, 0, 0);
    *(uint4*)(buf + (((size_t)b * 130 + y) * 130 + x) * 256 + chunk * 8) = z;
}

// ---------------- bilinear 2x upsample NCHW f32 -> padded NHWC bf16 ----------------
// One block per output row: loop all 8 c-slabs into a 64KB LDS row buffer, then
// flush 128px x 512B fully contiguous (no partial-line writes).
__global__ __launch_bounds__(256) void upsample_kernel(const float* __restrict__ x,
                                                       __bf16* __restrict__ xu) {
    int y = blockIdx.x;   // 0..127
    int b = blockIdx.y;   // 0..7
    __shared__ __bf16 orow[128 * 256];   // [px][ch] 64 KB
    int tid = threadIdx.x;

    int j = y >> 1;
    int y0, y1; float wy0, wy1;
    if (y & 1) { y0 = j; y1 = (j + 1 < 64) ? j + 1 : 63; wy0 = 0.75f; wy1 = 0.25f; }
    else       { y0 = (j - 1 >= 0) ? j - 1 : 0; y1 = j; wy0 = 0.25f; wy1 = 0.75f; }

    int c  = tid >> 3;          // 0..31
    int xs = (tid & 7) * 16;
    for (int ct = 0; ct < 8; ++ct) {
        int cc = ct * 32 + c;
        const float* row0 = x + ((size_t)(b * 256 + cc) * 64 + y0) * 64;
        const float* row1 = x + ((size_t)(b * 256 + cc) * 64 + y1) * 64;
#pragma unroll
        for (int k = 0; k < 16; ++k) {
            int xo = xs + k;
            int i = xo >> 1;
            int x0, x1; float wx0, wx1;
            if (xo & 1) { x0 = i; x1 = (i + 1 < 64) ? i + 1 : 63; wx0 = 0.75f; wx1 = 0.25f; }
            else        { x0 = (i - 1 >= 0) ? i - 1 : 0; x1 = i; wx0 = 0.25f; wx1 = 0.75f; }
            float v0 = wx0 * row0[x0] + wx1 * row0[x1];
            float v1 = wx0 * row1[x0] + wx1 * row1[x1];
            orow[xo * 256 + cc] = (__bf16)(wy0 * v0 + wy1 * v1);
        }
    }
    __syncthreads();
    // flush: 64 KB contiguous
    uint4* dst = (uint4*)(xu + (((size_t)(b * 130) + y + 1) * 130 + 1) * 256);
    const uint4* src = (const uint4*)orow;
#pragma unroll
    for (int it = 0; it < 16; ++it)
        dst[it * 256 + tid] = src[it * 256 + tid];
}

// ---------------- implicit-GEMM modulated conv, 256M x 128N tile, BK=32 ----------------
// Per block: batch b, one output row (128 px), ALL 256 out-channels.
// 4 waves of 128x64 (acc[8][4]) -> 12 ds_read_b128 per 32 MFMAs per wave (2x better
// amortization than 64x64). BK=32 -> 72 K-tiles, tap-minor/c0-major (L2-hot staging).
// LDS 48KB dbuf (declared 64KB for epilogue) -> 2 blocks/CU for cross-block overlap.
// XOR swizzle for 64B rows: chunk' = chunk ^ ((row>>1)&3)  (2-way conflicts = free).
template <int PHASE>
__global__ __launch_bounds__(256, 2) void conv_kernel(
    const __bf16* __restrict__ in,    // padded NHWC [8][130][130][256]
    const __bf16* __restrict__ wmall, // [8][256][9][256]
    float* __restrict__ outf,
    __bf16* __restrict__ outb) {
    __shared__ __attribute__((aligned(128))) char smem[65536];
    // sA: [2][256*32] bf16 = 32 KB at offset 0; sB: [2][128*32] = 16 KB at 32768
    const int tid  = threadIdx.x;
    const int bid  = blockIdx.x;
    // XCD-bijective swizzle: 1024 blocks = 8 XCDs x 128; one batch per XCD.
    const int swz  = (bid & 7) * 128 + (bid >> 3);
    const int b    = swz >> 7;
    const int yrow = swz & 127;
    const int lane = tid & 63;
    const int wv   = tid >> 6;          // 0..3
    const int wo   = (wv >> 1) * 128;   // wave M offset
    const int wn   = (wv & 1) * 64;     // wave N offset
    const int arow = lane & 15;
    const int cgb  = lane >> 4;         // 0..3
    const int xsw  = (cgb ^ ((arow >> 1) & 3)) * 16;   // read-side swizzle (bytes)
    // staging decomposition: lane -> (row-in-16, chunk-of-4), source pre-swizzled
    const int srow   = wv * 16 + (lane >> 2);          // 0..63
    const int chunkS = (lane & 3) ^ ((lane >> 3) & 3);
    const __bf16* wm_b = wmall + (size_t)b * 256 * 2304;
    const __bf16* arow_base = wm_b + (size_t)srow * 2304 + chunkS * 8;
    const __bf16* brow_base = in + ((size_t)((b * 130 + yrow) * 130 + srow)) * 256 + chunkS * 8;
    const int ldsA = (wv * 16) * 32;    // element offset of this wave's first A slab row
    const int ldsB = (wv * 16) * 32;

    f32x4 acc[8][4] = {};

#define STAGE(tt, buf)                                                          \
    {   const int tap = (tt) % 9, cb = (tt) / 9;                                \
        const size_t aoff = (size_t)(tap * 256 + cb * 32);                      \
        const size_t boff = (size_t)(((tap / 3) * 130 + (tap % 3)) * 256 + cb * 32); \
        __bf16* Ad = (__bf16*)smem + (buf) * 8192 + ldsA;                       \
        __bf16* Bd = (__bf16*)(smem + 32768) + (buf) * 4096 + ldsB;             \
        _Pragma("unroll")                                                       \
        for (int q = 0; q < 4; ++q)                                             \
            GLDS(arow_base + aoff + (size_t)q * 64 * 2304, Ad + q * 64 * 32);   \
        _Pragma("unroll")                                                       \
        for (int q = 0; q < 2; ++q)                                             \
            GLDS(brow_base + boff + (size_t)q * 64 * 256, Bd + q * 64 * 32);    \
    }

    // prologue: stage tile 0 (tap 0, c0=0) into buffer 0
    STAGE(0, 0);
    asm volatile("s_waitcnt vmcnt(0)" ::: "memory");
    __builtin_amdgcn_s_barrier();
    asm volatile("" ::: "memory");

    for (int t = 0; t < 72; ++t) {
        const int cur = t & 1;
        if (t < 71) STAGE(t + 1, cur ^ 1);
        const char* Ab = smem + cur * 16384 + (wo + arow) * 64 + xsw;
        const char* Bb = smem + 32768 + cur * 8192 + (wn + arow) * 64 + xsw;
        bf16x8 af[8], bfr[4];
#pragma unroll
        for (int jj = 0; jj < 4; ++jj) bfr[jj] = *(const bf16x8*)(Bb + jj * 1024);
#pragma unroll
        for (int m = 0; m < 8; ++m) af[m] = *(const bf16x8*)(Ab + m * 1024);
        __builtin_amdgcn_s_setprio(1);
#pragma unroll
        for (int m = 0; m < 8; ++m)
#pragma unroll
            for (int jj = 0; jj < 4; ++jj)
                acc[m][jj] = MFMA(af[m], bfr[jj], acc[m][jj]);
        __builtin_amdgcn_s_setprio(0);
        asm volatile("s_waitcnt vmcnt(0)" ::: "memory");
        __builtin_amdgcn_s_barrier();
        asm volatile("" ::: "memory");
    }
#undef STAGE

    // pin all pending LDS reads / MFMAs before reusing smem (rule #18)
    __builtin_amdgcn_sched_barrier(0);
    __syncthreads();

    if (PHASE == 1) {
        // stage output tile [n=128 px][256 och] bf16 (64 KB) into LDS, XOR-swizzled
        __bf16* const ot = (__bf16*)smem;
        const int cg = lane >> 4;
#pragma unroll
        for (int m = 0; m < 8; ++m)
#pragma unroll
            for (int jj = 0; jj < 4; ++jj) {
                int n  = wn + jj * 16 + arow;
                int ob = (wo + m * 16 + cg * 4) * 2;   // byte offset within 512B row
                union { __bf16 v[4]; uint2 u; } pk;
#pragma unroll
                for (int r = 0; r < 4; ++r) {
                    float v = acc[m][jj][r];
                    pk.v[r] = (__bf16)((v > 0.f) ? v : 0.2f * v);
                }
                *(uint2*)((char*)ot + n * 512 + (ob ^ ((n & 7) << 4))) = pk.u;
            }
        __syncthreads();
        // flush: 2 px per wave-instruction, 32 lanes x 16B = contiguous 512B per pixel
        const int half = lane >> 5;
        const int l32  = lane & 31;
#pragma unroll
        for (int it = 0; it < 16; ++it) {
            int n = wv * 32 + it * 2 + half;
            uint4 v = *(const uint4*)((const char*)ot + n * 512 + ((l32 * 16) ^ ((n & 7) << 4)));
            *(uint4*)(outb + (((size_t)(b * 130) + yrow + 1) * 130 + n + 1) * 256 + l32 * 8) = v;
        }
    } else {
        // NCHW f32: 16 lanes x 4B = contiguous 64B lines
#pragma unroll
        for (int m = 0; m < 8; ++m)
#pragma unroll
            for (int jj = 0; jj < 4; ++jj) {
                int o_base = wo + m * 16 + (lane >> 4) * 4;
                int n      = wn + jj * 16 + (lane & 15);
#pragma unroll
                for (int r = 0; r < 4; ++r) {
                    float v = acc[m][jj][r];
                    v = (v > 0.f) ? v : 0.2f * v;
                    outf[((size_t)(b * 256 + o_base + r) * 128 + yrow) * 128 + n] = v;
                }
            }
    }
}

extern "C" void kernel_launch(void* const* d_in, const int* in_sizes, int n_in,
                              void* d_out, int out_size, void* d_ws, size_t ws_size,
                              hipStream_t stream) {
    const float* x      = (const float*)d_in[0];
    const float* istyle = (const float*)d_in[1];
    const float* ws1    = (const float*)d_in[2];
    const float* bs1    = (const float*)d_in[3];
    const float* w1     = (const float*)d_in[4];
    const float* ws2    = (const float*)d_in[5];
    const float* bs2    = (const float*)d_in[6];
    const float* w2     = (const float*)d_in[7];
    float* out = (float*)d_out;

    char* ws = (char*)d_ws;
    __bf16* xu_p = (__bf16*)(ws);
    __bf16* y1_p = (__bf16*)(ws + 69222400);
    __bf16* wm   = (__bf16*)(ws + 138444800);
    float*  sbuf = (float*)(ws + 147881984);

    style_kernel<<<dim3(8, 2), 256, 0, stream>>>(istyle, ws1, bs1, ws2, bs2, sbuf);
    zeropad_kernel<<<dim3(65, 8, 2), 256, 0, stream>>>(xu_p, y1_p);
    upsample_kernel<<<dim3(128, 8), 256, 0, stream>>>(x, xu_p);
    modw_kernel<<<dim3(512), 256, 0, stream>>>(w1, sbuf, wm);
    conv_kernel<1><<<dim3(1024), 256, 0, stream>>>(xu_p, wm, nullptr, y1_p);
    modw_kernel<<<dim3(512), 256, 0, stream>>>(w2, sbuf + 2048, wm);
    conv_kernel<2><<<dim3(1024), 256, 0, stream>>>(y1_p, wm, out, nullptr);
}